// Round 13
// baseline (244.494 us; speedup 1.0000x reference)
//
#include <hip/hip_runtime.h>
#include <math.h>

#define T_DIM 2048
#define N_DIM 64
#define E_DIM 1024
#define A_DIM 256
#define TCHUNK 64
#define NCHUNK (T_DIM / TCHUNK)  // 32

typedef __bf16 bf16x8 __attribute__((ext_vector_type(8)));
typedef __bf16 bf16x4 __attribute__((ext_vector_type(4)));
typedef float f32x4 __attribute__((ext_vector_type(4)));

__device__ __forceinline__ float tanh_fast(float x) {
    float xc = fminf(fmaxf(x, -15.f), 15.f);
    float e = __expf(2.f * xc);
    return (e - 1.f) / (e + 1.f);
}

// LDS-write-ordering barrier that does NOT drain outstanding global loads.
__device__ __forceinline__ void lds_barrier() {
    asm volatile("s_waitcnt lgkmcnt(0)\n\ts_barrier" ::: "memory");
}

// ---- fused prep: blocks 0..127 convert W_e -> bf16 permuted Wp;
//      blocks 128..191 compute d_proj[n][a].
__global__ __launch_bounds__(256) void prep_kernel(
    const float* __restrict__ W_e, const float* __restrict__ dec_h,
    const float* __restrict__ W_d, __bf16* __restrict__ Wp,
    float* __restrict__ d_proj) {
    __shared__ float dec[E_DIM];
    const int tid = threadIdx.x;
    if (blockIdx.x < 128) {
        const int uid = blockIdx.x * 256 + tid;
        const int a = uid >> 7;
        const int c = uid & 127;
        const float4* src = (const float4*)(W_e + (size_t)a * E_DIM + c * 8);
        float4 x0 = src[0], x1 = src[1];
        bf16x8 o;
        o[0] = (__bf16)x0.x; o[1] = (__bf16)x0.y; o[2] = (__bf16)x0.z; o[3] = (__bf16)x0.w;
        o[4] = (__bf16)x1.x; o[5] = (__bf16)x1.y; o[6] = (__bf16)x1.z; o[7] = (__bf16)x1.w;
        *(bf16x8*)(Wp + ((size_t)c * 256 + a) * 8) = o;
    } else {
        const int n = blockIdx.x - 128;
        reinterpret_cast<float4*>(dec)[tid] =
            reinterpret_cast<const float4*>(dec_h + (size_t)n * E_DIM)[tid];
        __syncthreads();
        const float* w = W_d + (size_t)tid * E_DIM;
        float acc = 0.f;
#pragma unroll 4
        for (int e = 0; e < E_DIM; e += 4) {
            float4 wv = *reinterpret_cast<const float4*>(w + e);
            acc = fmaf(wv.x, dec[e], acc);
            acc = fmaf(wv.y, dec[e + 1], acc);
            acc = fmaf(wv.z, dec[e + 2], acc);
            acc = fmaf(wv.w, dec[e + 3], acc);
        }
        d_proj[n * A_DIM + tid] = acc;
    }
}

// ---- flash: block=(n, 64-t chunk), 512 thr = 8 waves, wave = 64 rows x 32
// a-cols. 128 KB persistent LDS A-tile (1 block/CU). KSTEP=256, 4 barriers.
// B traffic HALVED vs TCHUNK=32 (Wp re-read once per 64 rows, not per 32).
__global__ __launch_bounds__(512, 2) void flash_kernel(
    const float* __restrict__ enc, const __bf16* __restrict__ Wp,
    const float* __restrict__ dproj, const float* __restrict__ v,
    float* __restrict__ scores, float* __restrict__ partial,
    float* __restrict__ ms, float* __restrict__ zs) {
    __shared__ __align__(16) __bf16 Atile[TCHUNK * E_DIM];  // 128 KB
    // tail overlay: red[512] + wls[64] = 2304 B (units 8048..8191 = ks31,g>=1
    // region); written only after the post-MFMA barrier; weighted-sum slots
    // with ks==31 && g>=1 read from global instead.
    float* red = ((float*)Atile) + 32768 - 576;
    float* wls = red + 512;

    const int tid = threadIdx.x;
    const int bid = blockIdx.x;
    const int n = bid & (N_DIM - 1);
    const int c = bid >> 6;  // 0..31
    const int t0 = c * TCHUNK;
    const int wn = tid >> 6;  // wave 0..7 -> a-cols wn*32..+32
    const int lane = tid & 63;
    const int lr = lane & 15, lg = lane >> 4;

    f32x4 acc[4][2];
#pragma unroll
    for (int i = 0; i < 4; ++i)
#pragma unroll
        for (int j = 0; j < 2; ++j) acc[i][j] = (f32x4){0.f, 0.f, 0.f, 0.f};

    float vv[2], dp[2];
#pragma unroll
    for (int fn = 0; fn < 2; ++fn) {
        const int a = wn * 32 + fn * 16 + lr;
        vv[fn] = v[a];
        dp[fn] = dproj[n * A_DIM + a];
    }

    // staging: thread (srow 0..63, sg8 0..7); per iter loads cols
    // it*256 + sg8*4 + j*32 (j=0..7) of its row (8 lanes x 16B = 128B segs).
    const int srow = tid >> 3, sg8 = tid & 7;
    const int sgg = (sg8 >> 1) & 3, sbh = sg8 & 1;
    const float* encRow =
        enc + ((size_t)(t0 + srow) * N_DIM + n) * E_DIM + sg8 * 4;
    const bf16x8* WpV = (const bf16x8*)Wp;
    const int bfoff = lg * 256 + wn * 32 + lr;  // + fn*16 + ks*1024

    // prologue: A chunk 0 in flight; Bcur = ks {0,1}
    float4 a0 = *(const float4*)(encRow);
    float4 a1 = *(const float4*)(encRow + 32);
    float4 a2 = *(const float4*)(encRow + 64);
    float4 a3 = *(const float4*)(encRow + 96);
    float4 a4_ = *(const float4*)(encRow + 128);
    float4 a5 = *(const float4*)(encRow + 160);
    float4 a6 = *(const float4*)(encRow + 192);
    float4 a7 = *(const float4*)(encRow + 224);
    bf16x8 Bcur[2][2];
#pragma unroll
    for (int s = 0; s < 2; ++s)
#pragma unroll
        for (int fn = 0; fn < 2; ++fn)
            Bcur[s][fn] = WpV[(size_t)s * 1024 + bfoff + fn * 16];

#pragma unroll
    for (int it = 0; it < 4; ++it) {
        // cvt + write A chunk it into slots it*8 + j (write-once)
        {
#pragma unroll
            for (int j = 0; j < 8; ++j) {
                float4 aj = (j == 0) ? a0 : (j == 1) ? a1 : (j == 2) ? a2
                          : (j == 3) ? a3 : (j == 4) ? a4_ : (j == 5) ? a5
                          : (j == 6) ? a6 : a7;
                bf16x4 w;
                w[0] = (__bf16)aj.x; w[1] = (__bf16)aj.y;
                w[2] = (__bf16)aj.z; w[3] = (__bf16)aj.w;
                const int ks = it * 8 + j;
                const int q = (4 * j + sgg) & 7;  // (ks*4+sgg)&7
                const int u = ks * 256 + sgg * 64 + (srow ^ q);
                *(bf16x4*)((char*)Atile + u * 16 + sbh * 8) = w;
            }
        }
        // issue A chunk it+1 (stays in flight across the barrier)
        if (it < 3) {
            const float* p = encRow + (it + 1) * 256;
            a0 = *(const float4*)(p);
            a1 = *(const float4*)(p + 32);
            a2 = *(const float4*)(p + 64);
            a3 = *(const float4*)(p + 96);
            a4_ = *(const float4*)(p + 128);
            a5 = *(const float4*)(p + 160);
            a6 = *(const float4*)(p + 192);
            a7 = *(const float4*)(p + 224);
        }
        lds_barrier();  // orders ds_writes only; global loads NOT drained
        // 4 MFMA batches of 2 ks each; B loaded one batch ahead
#pragma unroll
        for (int b = 0; b < 4; ++b) {
            const int ksb = it * 8 + b * 2;
            bf16x8 Bnxt[2][2];
            if (!(it == 3 && b == 3)) {
                const int ksn = (b < 3) ? ksb + 2 : (it + 1) * 8;
#pragma unroll
                for (int s = 0; s < 2; ++s)
#pragma unroll
                    for (int fn = 0; fn < 2; ++fn)
                        Bnxt[s][fn] =
                            WpV[(size_t)(ksn + s) * 1024 + bfoff + fn * 16];
            }
#pragma unroll
            for (int s = 0; s < 2; ++s) {
                const int ks = ksb + s;
#pragma unroll
                for (int fm = 0; fm < 4; ++fm) {
                    const int u = ks * 256 + lg * 64 +
                                  ((fm * 16 + lr) ^ ((ks * 4 + lg) & 7));
                    bf16x8 af = *(const bf16x8*)((const char*)Atile + u * 16);
                    acc[fm][0] = __builtin_amdgcn_mfma_f32_16x16x32_bf16(
                        af, Bcur[s][0], acc[fm][0], 0, 0, 0);
                    acc[fm][1] = __builtin_amdgcn_mfma_f32_16x16x32_bf16(
                        af, Bcur[s][1], acc[fm][1], 0, 0, 0);
                }
            }
#pragma unroll
            for (int s = 0; s < 2; ++s)
#pragma unroll
                for (int fn = 0; fn < 2; ++fn) Bcur[s][fn] = Bnxt[s][fn];
        }
    }

    // ---- scores epilogue: 64 rows ----
    float pr[4][4];
#pragma unroll
    for (int fm = 0; fm < 4; ++fm) {
#pragma unroll
        for (int reg = 0; reg < 4; ++reg) {
            float p = fmaf(vv[0], tanh_fast(acc[fm][0][reg] + dp[0]), 0.f);
            p = fmaf(vv[1], tanh_fast(acc[fm][1][reg] + dp[1]), p);
            p += __shfl_xor(p, 1);
            p += __shfl_xor(p, 2);
            p += __shfl_xor(p, 4);
            p += __shfl_xor(p, 8);
            pr[fm][reg] = p;
        }
    }
    __syncthreads();  // all MFMA LDS reads done -> overlay safe
    if (lr == 0) {
#pragma unroll
        for (int fm = 0; fm < 4; ++fm)
#pragma unroll
            for (int reg = 0; reg < 4; ++reg)
                red[wn * 64 + fm * 16 + lg * 4 + reg] = pr[fm][reg];
    }
    __syncthreads();
    if (tid < TCHUNK) {
        float s = 0.f;
#pragma unroll
        for (int w = 0; w < 8; ++w) s += red[w * 64 + tid];
        scores[(t0 + tid) * N_DIM + n] = s;
        if (partial) {
            float m = s;
            m = fmaxf(m, __shfl_xor(m, 1));
            m = fmaxf(m, __shfl_xor(m, 2));
            m = fmaxf(m, __shfl_xor(m, 4));
            m = fmaxf(m, __shfl_xor(m, 8));
            m = fmaxf(m, __shfl_xor(m, 16));
            m = fmaxf(m, __shfl_xor(m, 32));
            float w = __expf(s - m);
            float Z = w;
            Z += __shfl_xor(Z, 1);
            Z += __shfl_xor(Z, 2);
            Z += __shfl_xor(Z, 4);
            Z += __shfl_xor(Z, 8);
            Z += __shfl_xor(Z, 16);
            Z += __shfl_xor(Z, 32);
            wls[tid] = w;
            if (tid == 0) {
                ms[n * NCHUNK + c] = m;
                zs[n * NCHUNK + c] = Z;
            }
        }
    }
    __syncthreads();

    if (!partial) return;
    // ---- weighted row-sum from LDS tile -> ctx partial ----
    // 256 col-slots (ks,g,bh) x 2 row-halves; each thread sums 32 rows.
    const int cs = tid >> 1, rh = tid & 1;
    const int ks = cs >> 3, gg = (cs >> 1) & 3, bh = cs & 1;
    const int colbase = ks * 32 + gg * 8 + bh * 4;
    f32x4 a4 = (f32x4){0.f, 0.f, 0.f, 0.f};
    if (!(ks == 31 && gg >= 1)) {  // overlay-covered slots excluded
        const int q = (ks * 4 + gg) & 7;
        const int ubase = ks * 256 + gg * 64;
#pragma unroll 4
        for (int r = rh * 32; r < rh * 32 + 32; ++r) {
            const float w = wls[r];
            bf16x4 ev = *(const bf16x4*)((const char*)Atile +
                                         (ubase + (r ^ q)) * 16 + bh * 8);
            a4[0] = fmaf(w, (float)ev[0], a4[0]);
            a4[1] = fmaf(w, (float)ev[1], a4[1]);
            a4[2] = fmaf(w, (float)ev[2], a4[2]);
            a4[3] = fmaf(w, (float)ev[3], a4[3]);
        }
    } else {  // overlay region: re-read those columns from cache
#pragma unroll 4
        for (int r = rh * 32; r < rh * 32 + 32; ++r) {
            const float w = wls[r];
            float4 ev = *(const float4*)(
                enc + ((size_t)(t0 + r) * N_DIM + n) * E_DIM + colbase);
            a4[0] = fmaf(w, ev.x, a4[0]);
            a4[1] = fmaf(w, ev.y, a4[1]);
            a4[2] = fmaf(w, ev.z, a4[2]);
            a4[3] = fmaf(w, ev.w, a4[3]);
        }
    }
#pragma unroll
    for (int k = 0; k < 4; ++k) a4[k] += __shfl_xor(a4[k], 1);
    if (rh == 0)
        *(f32x4*)(partial + ((size_t)c * N_DIM + n) * E_DIM + colbase) = a4;
}

// ---- combine: per n, flash rescale of 32 chunk partials + alpha ----
__global__ __launch_bounds__(256) void combine_kernel(
    const float* __restrict__ partial, const float* __restrict__ ms,
    const float* __restrict__ zs, const float* __restrict__ scores,
    float* __restrict__ ctx, float* __restrict__ alpha) {
    __shared__ float scale[NCHUNK];
    __shared__ float MZ[2];
    const int n = blockIdx.x;
    const int tid = threadIdx.x;
    if (tid < NCHUNK) {
        float m = ms[n * NCHUNK + tid];
        float M = m;
        M = fmaxf(M, __shfl_xor(M, 1));
        M = fmaxf(M, __shfl_xor(M, 2));
        M = fmaxf(M, __shfl_xor(M, 4));
        M = fmaxf(M, __shfl_xor(M, 8));
        M = fmaxf(M, __shfl_xor(M, 16));
        float e = __expf(m - M);
        float z = zs[n * NCHUNK + tid] * e;
        float Z = z;
        Z += __shfl_xor(Z, 1);
        Z += __shfl_xor(Z, 2);
        Z += __shfl_xor(Z, 4);
        Z += __shfl_xor(Z, 8);
        Z += __shfl_xor(Z, 16);
        scale[tid] = e;
        if (tid == 0) {
            MZ[0] = M;
            MZ[1] = Z;
        }
    }
    __syncthreads();
    const float M = MZ[0];
    const float invZ = 1.f / MZ[1];
    f32x4 a4 = (f32x4){0.f, 0.f, 0.f, 0.f};
#pragma unroll 4
    for (int c = 0; c < NCHUNK; ++c) {
        const float s = scale[c] * invZ;
        float4 p = *(const float4*)(partial +
                                    ((size_t)c * N_DIM + n) * E_DIM + tid * 4);
        a4[0] = fmaf(s, p.x, a4[0]);
        a4[1] = fmaf(s, p.y, a4[1]);
        a4[2] = fmaf(s, p.z, a4[2]);
        a4[3] = fmaf(s, p.w, a4[3]);
    }
    *(f32x4*)(ctx + (size_t)n * E_DIM + tid * 4) = a4;
    for (int t = tid; t < T_DIM; t += 256)
        alpha[t * N_DIM + n] = __expf(scores[t * N_DIM + n] - M) * invZ;
}

// ---------------- fallback path (small ws): softmax + fp32 ctx ------------
__global__ __launch_bounds__(256) void softmax_kernel(
    const float* __restrict__ scores, float* __restrict__ alpha) {
    __shared__ float red[256];
    const int n = blockIdx.x;
    const int tid = threadIdx.x;
    float m = -3.4e38f;
    for (int t = tid; t < T_DIM; t += 256)
        m = fmaxf(m, scores[t * N_DIM + n]);
    red[tid] = m;
    __syncthreads();
    for (int s = 128; s; s >>= 1) {
        if (tid < s) red[tid] = fmaxf(red[tid], red[tid + s]);
        __syncthreads();
    }
    m = red[0];
    __syncthreads();
    float sum = 0.f;
    for (int t = tid; t < T_DIM; t += 256)
        sum += expf(scores[t * N_DIM + n] - m);
    red[tid] = sum;
    __syncthreads();
    for (int s = 128; s; s >>= 1) {
        if (tid < s) red[tid] += red[tid + s];
        __syncthreads();
    }
    const float inv = 1.f / red[0];
    for (int t = tid; t < T_DIM; t += 256)
        alpha[t * N_DIM + n] = expf(scores[t * N_DIM + n] - m) * inv;
}

__global__ __launch_bounds__(256) void ctx_f32(const float* __restrict__ enc,
                                               const float* __restrict__ alpha,
                                               float* __restrict__ ctx) {
    const int n = blockIdx.x;
    const int tid = threadIdx.x;
    float4 acc = {0.f, 0.f, 0.f, 0.f};
    for (int t = 0; t < T_DIM; ++t) {
        const float al = alpha[t * N_DIM + n];
        float4 ev = *reinterpret_cast<const float4*>(
            enc + (size_t)(t * N_DIM + n) * E_DIM + tid * 4);
        acc.x = fmaf(al, ev.x, acc.x);
        acc.y = fmaf(al, ev.y, acc.y);
        acc.z = fmaf(al, ev.z, acc.z);
        acc.w = fmaf(al, ev.w, acc.w);
    }
    *reinterpret_cast<float4*>(ctx + (size_t)n * E_DIM + tid * 4) = acc;
}

extern "C" void kernel_launch(void* const* d_in, const int* in_sizes, int n_in,
                              void* d_out, int out_size, void* d_ws,
                              size_t ws_size, hipStream_t stream) {
    const float* enc = (const float*)d_in[0];    // [T,N,E]
    const float* dec_h = (const float*)d_in[1];  // [N,D]
    const float* W_e = (const float*)d_in[2];    // [A,E]
    const float* W_d = (const float*)d_in[3];    // [A,D]
    const float* v = (const float*)d_in[4];      // [1,A]

    float* out = (float*)d_out;
    float* ctx = out;            // 64*1024
    float* alpha = out + 65536;  // 2048*64

    float* ws = (float*)d_ws;
    float* d_proj = ws;                   // 16384 f
    float* scores = ws + 16384;           // 131072 f
    __bf16* Wp = (__bf16*)(ws + 147456);  // 131072 f worth
    float* ms = ws + 278528;              // 4096 f (2048 used)
    float* zs = ws + 282624;              // 4096 f (2048 used)
    float* partial = ws + 286720;         // 32*65536 = 2097152 f

    const size_t need =
        (size_t)(286720 + NCHUNK * N_DIM * E_DIM) * sizeof(float);
    const bool big = ws_size >= need;

    prep_kernel<<<192, 256, 0, stream>>>(W_e, dec_h, W_d, Wp, d_proj);
    flash_kernel<<<T_DIM / TCHUNK * N_DIM, 512, 0, stream>>>(
        enc, Wp, d_proj, v, scores, big ? partial : nullptr, ms, zs);
    if (big) {
        combine_kernel<<<N_DIM, 256, 0, stream>>>(partial, ms, zs, scores,
                                                  ctx, alpha);
    } else {
        softmax_kernel<<<N_DIM, 256, 0, stream>>>(scores, alpha);
        ctx_f32<<<N_DIM, 256, 0, stream>>>(enc, alpha, ctx);
    }
}

// Round 14
// 213.446 us; speedup vs baseline: 1.1455x; 1.1455x over previous
//
#include <hip/hip_runtime.h>
#include <math.h>

#define T_DIM 2048
#define N_DIM 64
#define E_DIM 1024
#define A_DIM 256
#define TCHUNK 32
#define NCHUNK (T_DIM / TCHUNK)  // 64

typedef __bf16 bf16x8 __attribute__((ext_vector_type(8)));
typedef __bf16 bf16x4 __attribute__((ext_vector_type(4)));
typedef float f32x4 __attribute__((ext_vector_type(4)));

__device__ __forceinline__ float tanh_fast(float x) {
    float xc = fminf(fmaxf(x, -15.f), 15.f);
    float e = __expf(2.f * xc);
    return (e - 1.f) / (e + 1.f);
}

// LDS-write-ordering barrier that does NOT drain outstanding global loads.
__device__ __forceinline__ void lds_barrier() {
    asm volatile("s_waitcnt lgkmcnt(0)\n\ts_barrier" ::: "memory");
}

// ---- fused prep: blocks 0..127 convert W_e -> bf16 permuted Wp;
//      blocks 128..191 compute d_proj[n][a].
__global__ __launch_bounds__(256) void prep_kernel(
    const float* __restrict__ W_e, const float* __restrict__ dec_h,
    const float* __restrict__ W_d, __bf16* __restrict__ Wp,
    float* __restrict__ d_proj) {
    __shared__ float dec[E_DIM];
    const int tid = threadIdx.x;
    if (blockIdx.x < 128) {
        const int uid = blockIdx.x * 256 + tid;
        const int a = uid >> 7;
        const int c = uid & 127;
        const float4* src = (const float4*)(W_e + (size_t)a * E_DIM + c * 8);
        float4 x0 = src[0], x1 = src[1];
        bf16x8 o;
        o[0] = (__bf16)x0.x; o[1] = (__bf16)x0.y; o[2] = (__bf16)x0.z; o[3] = (__bf16)x0.w;
        o[4] = (__bf16)x1.x; o[5] = (__bf16)x1.y; o[6] = (__bf16)x1.z; o[7] = (__bf16)x1.w;
        *(bf16x8*)(Wp + ((size_t)c * 256 + a) * 8) = o;
    } else {
        const int n = blockIdx.x - 128;
        reinterpret_cast<float4*>(dec)[tid] =
            reinterpret_cast<const float4*>(dec_h + (size_t)n * E_DIM)[tid];
        __syncthreads();
        const float* w = W_d + (size_t)tid * E_DIM;
        float acc = 0.f;
#pragma unroll 4
        for (int e = 0; e < E_DIM; e += 4) {
            float4 wv = *reinterpret_cast<const float4*>(w + e);
            acc = fmaf(wv.x, dec[e], acc);
            acc = fmaf(wv.y, dec[e + 1], acc);
            acc = fmaf(wv.z, dec[e + 2], acc);
            acc = fmaf(wv.w, dec[e + 3], acc);
        }
        d_proj[n * A_DIM + tid] = acc;
    }
}

// ---- flash: block=(n, 32-t chunk), 512 thr = 8 waves (32 a-cols each).
// KSTEP=256 per lgkm-barrier (4 barriers). K-iteration order rotated by block
// parity so co-resident blocks are phase-decorrelated. K order is free: the
// GEMM is a sum. Best-measured configuration (round 12, 213.8 us).
__global__ __launch_bounds__(512, 4) void flash_kernel(
    const float* __restrict__ enc, const __bf16* __restrict__ Wp,
    const float* __restrict__ dproj, const float* __restrict__ v,
    float* __restrict__ scores, float* __restrict__ partial,
    float* __restrict__ ms, float* __restrict__ zs) {
    __shared__ __align__(16) __bf16 Atile[TCHUNK * E_DIM];  // 64 KB persistent
    float* red = ((float*)Atile) + 16384 - 288;  // tail overlay: red[256]
    float* wls = red + 256;                      // + wls[32]

    const int tid = threadIdx.x;
    const int bid = blockIdx.x;
    const int n = bid & (N_DIM - 1);
    const int c = bid >> 6;
    const int t0 = c * TCHUNK;
    const int ph = (bid & 1) * 2;  // phase stagger for co-resident blocks
    const int wn = tid >> 6;  // wave 0..7 -> a-cols wn*32..+32
    const int lane = tid & 63;
    const int lr = lane & 15, lg = lane >> 4;

    f32x4 acc[2][2];
#pragma unroll
    for (int i = 0; i < 2; ++i)
#pragma unroll
        for (int j = 0; j < 2; ++j) acc[i][j] = (f32x4){0.f, 0.f, 0.f, 0.f};

    float vv[2], dp[2];
#pragma unroll
    for (int fn = 0; fn < 2; ++fn) {
        const int a = wn * 32 + fn * 16 + lr;
        vv[fn] = v[a];
        dp[fn] = dproj[n * A_DIM + a];
    }

    // staging map: thread (srow 0..31, sg 0..15); per iter loads cols
    // it*256 + sg*4 + {0,64,128,192} (each load: 16 lanes x contiguous 16B).
    const int srow = tid >> 4, sg = tid & 15;
    const int sksb = sg >> 3;         // 0/1
    const int sgg = (sg & 7) >> 1;    // 8-col group within ks
    const int sbh = sg & 1;           // 8B half
    const float* encRow =
        enc + ((size_t)(t0 + srow) * N_DIM + n) * E_DIM + sg * 4;
    const bf16x8* WpV = (const bf16x8*)Wp;
    const int bfoff = lg * 256 + wn * 32 + lr;  // + fn*16 + ks*1024

    // prologue: A chunk (first in permuted order) in flight; Bcur = its ks
    float4 a0, a1, a2, a3;
    {
        const float* p = encRow + ph * 256;
        a0 = *(const float4*)p;
        a1 = *(const float4*)(p + 64);
        a2 = *(const float4*)(p + 128);
        a3 = *(const float4*)(p + 192);
    }
    bf16x8 Bcur[2][2];
#pragma unroll
    for (int s = 0; s < 2; ++s)
#pragma unroll
        for (int fn = 0; fn < 2; ++fn)
            Bcur[s][fn] = WpV[(size_t)(ph * 8 + s) * 1024 + bfoff + fn * 16];

#pragma unroll
    for (int i = 0; i < 4; ++i) {
        const int it = (i + ph) & 3;        // permuted K-phase
        const int itn = (i + 1 + ph) & 3;   // next in sequence
        // cvt + write A chunk it into slots it*8 + sksb + {0,2,4,6}
        {
            bf16x4 w0, w1, w2, w3;
            w0[0] = (__bf16)a0.x; w0[1] = (__bf16)a0.y; w0[2] = (__bf16)a0.z; w0[3] = (__bf16)a0.w;
            w1[0] = (__bf16)a1.x; w1[1] = (__bf16)a1.y; w1[2] = (__bf16)a1.z; w1[3] = (__bf16)a1.w;
            w2[0] = (__bf16)a2.x; w2[1] = (__bf16)a2.y; w2[2] = (__bf16)a2.z; w2[3] = (__bf16)a2.w;
            w3[0] = (__bf16)a3.x; w3[1] = (__bf16)a3.y; w3[2] = (__bf16)a3.z; w3[3] = (__bf16)a3.w;
            const int k0 = it * 8 + sksb;
#pragma unroll
            for (int j = 0; j < 4; ++j) {
                const int ks = k0 + j * 2;
                const int u = ks * 128 + sgg * 32 + (srow ^ ((ks * 4 + sgg) & 7));
                bf16x4 w = (j == 0) ? w0 : (j == 1) ? w1 : (j == 2) ? w2 : w3;
                *(bf16x4*)((char*)Atile + u * 16 + sbh * 8) = w;
            }
        }
        // issue A chunk for next permuted iter (in flight across the barrier)
        if (i < 3) {
            const float* p = encRow + itn * 256;
            a0 = *(const float4*)p;
            a1 = *(const float4*)(p + 64);
            a2 = *(const float4*)(p + 128);
            a3 = *(const float4*)(p + 192);
        }
        lds_barrier();  // orders ds_writes only; global loads NOT drained
        // 4 MFMA batches of 2 ks each; B loaded one batch ahead
#pragma unroll
        for (int b = 0; b < 4; ++b) {
            const int ksb = it * 8 + b * 2;
            bf16x8 Bnxt[2][2];
            if (!(i == 3 && b == 3)) {
                const int ksn = (b < 3) ? ksb + 2 : itn * 8;
#pragma unroll
                for (int s = 0; s < 2; ++s)
#pragma unroll
                    for (int fn = 0; fn < 2; ++fn)
                        Bnxt[s][fn] =
                            WpV[(size_t)(ksn + s) * 1024 + bfoff + fn * 16];
            }
#pragma unroll
            for (int s = 0; s < 2; ++s) {
                const int ks = ksb + s;
#pragma unroll
                for (int fm = 0; fm < 2; ++fm) {
                    const int u = ks * 128 + lg * 32 +
                                  ((fm * 16 + lr) ^ ((ks * 4 + lg) & 7));
                    bf16x8 af = *(const bf16x8*)((const char*)Atile + u * 16);
                    acc[fm][0] = __builtin_amdgcn_mfma_f32_16x16x32_bf16(
                        af, Bcur[s][0], acc[fm][0], 0, 0, 0);
                    acc[fm][1] = __builtin_amdgcn_mfma_f32_16x16x32_bf16(
                        af, Bcur[s][1], acc[fm][1], 0, 0, 0);
                }
            }
#pragma unroll
            for (int s = 0; s < 2; ++s)
#pragma unroll
                for (int fn = 0; fn < 2; ++fn) Bcur[s][fn] = Bnxt[s][fn];
        }
    }

    // ---- scores epilogue ----
    float pr[2][4];
#pragma unroll
    for (int fm = 0; fm < 2; ++fm) {
#pragma unroll
        for (int reg = 0; reg < 4; ++reg) {
            float p = fmaf(vv[0], tanh_fast(acc[fm][0][reg] + dp[0]), 0.f);
            p = fmaf(vv[1], tanh_fast(acc[fm][1][reg] + dp[1]), p);
            p += __shfl_xor(p, 1);
            p += __shfl_xor(p, 2);
            p += __shfl_xor(p, 4);
            p += __shfl_xor(p, 8);
            pr[fm][reg] = p;
        }
    }
    __syncthreads();  // all MFMA LDS reads done -> overlay safe
    if (lr == 0) {
#pragma unroll
        for (int fm = 0; fm < 2; ++fm)
#pragma unroll
            for (int reg = 0; reg < 4; ++reg)
                red[wn * 32 + fm * 16 + lg * 4 + reg] = pr[fm][reg];
    }
    __syncthreads();
    if (tid < TCHUNK) {
        float s = 0.f;
#pragma unroll
        for (int w = 0; w < 8; ++w) s += red[w * 32 + tid];
        scores[(t0 + tid) * N_DIM + n] = s;
        if (partial) {
            float m = s;
            m = fmaxf(m, __shfl_xor(m, 1));
            m = fmaxf(m, __shfl_xor(m, 2));
            m = fmaxf(m, __shfl_xor(m, 4));
            m = fmaxf(m, __shfl_xor(m, 8));
            m = fmaxf(m, __shfl_xor(m, 16));
            float w = __expf(s - m);
            float Z = w;
            Z += __shfl_xor(Z, 1);
            Z += __shfl_xor(Z, 2);
            Z += __shfl_xor(Z, 4);
            Z += __shfl_xor(Z, 8);
            Z += __shfl_xor(Z, 16);
            wls[tid] = w;
            if (tid == 0) {
                ms[n * NCHUNK + c] = m;
                zs[n * NCHUNK + c] = Z;
            }
        }
    }
    __syncthreads();

    if (!partial) return;
    // ---- weighted row-sum from LDS tile -> ctx partial ----
    const int cs = tid >> 1, rh = tid & 1;
    const int ks = cs >> 3, gg = (cs >> 1) & 3, bh = cs & 1;
    const int colbase = ks * 32 + gg * 8 + bh * 4;
    f32x4 a4 = (f32x4){0.f, 0.f, 0.f, 0.f};
    if (cs < 250) {  // slots under the red/wls overlay excluded
        const int q = (ks * 4 + gg) & 7;
        const int ubase = ks * 128 + gg * 32;
#pragma unroll 4
        for (int r = rh * 16; r < rh * 16 + 16; ++r) {
            const float w = wls[r];
            bf16x4 ev = *(const bf16x4*)((const char*)Atile +
                                         (ubase + (r ^ q)) * 16 + bh * 8);
            a4[0] = fmaf(w, (float)ev[0], a4[0]);
            a4[1] = fmaf(w, (float)ev[1], a4[1]);
            a4[2] = fmaf(w, (float)ev[2], a4[2]);
            a4[3] = fmaf(w, (float)ev[3], a4[3]);
        }
    } else {  // overlay region: re-read those columns from cache
#pragma unroll 4
        for (int r = rh * 16; r < rh * 16 + 16; ++r) {
            const float w = wls[r];
            float4 ev = *(const float4*)(
                enc + ((size_t)(t0 + r) * N_DIM + n) * E_DIM + colbase);
            a4[0] = fmaf(w, ev.x, a4[0]);
            a4[1] = fmaf(w, ev.y, a4[1]);
            a4[2] = fmaf(w, ev.z, a4[2]);
            a4[3] = fmaf(w, ev.w, a4[3]);
        }
    }
#pragma unroll
    for (int k = 0; k < 4; ++k) a4[k] += __shfl_xor(a4[k], 1);
    if (rh == 0)
        *(f32x4*)(partial + ((size_t)c * N_DIM + n) * E_DIM + colbase) = a4;
}

// ---- combine: per n, flash rescale of 64 chunk partials + alpha ----
__global__ __launch_bounds__(256) void combine_kernel(
    const float* __restrict__ partial, const float* __restrict__ ms,
    const float* __restrict__ zs, const float* __restrict__ scores,
    float* __restrict__ ctx, float* __restrict__ alpha) {
    __shared__ float scale[NCHUNK];
    __shared__ float MZ[2];
    const int n = blockIdx.x;
    const int tid = threadIdx.x;
    if (tid < NCHUNK) {
        float m = ms[n * NCHUNK + tid];
        float M = m;
        M = fmaxf(M, __shfl_xor(M, 1));
        M = fmaxf(M, __shfl_xor(M, 2));
        M = fmaxf(M, __shfl_xor(M, 4));
        M = fmaxf(M, __shfl_xor(M, 8));
        M = fmaxf(M, __shfl_xor(M, 16));
        M = fmaxf(M, __shfl_xor(M, 32));
        float e = __expf(m - M);
        float z = zs[n * NCHUNK + tid] * e;
        float Z = z;
        Z += __shfl_xor(Z, 1);
        Z += __shfl_xor(Z, 2);
        Z += __shfl_xor(Z, 4);
        Z += __shfl_xor(Z, 8);
        Z += __shfl_xor(Z, 16);
        Z += __shfl_xor(Z, 32);
        scale[tid] = e;
        if (tid == 0) {
            MZ[0] = M;
            MZ[1] = Z;
        }
    }
    __syncthreads();
    const float M = MZ[0];
    const float invZ = 1.f / MZ[1];
    f32x4 a4 = (f32x4){0.f, 0.f, 0.f, 0.f};
#pragma unroll 4
    for (int c = 0; c < NCHUNK; ++c) {
        const float s = scale[c] * invZ;
        float4 p = *(const float4*)(partial +
                                    ((size_t)c * N_DIM + n) * E_DIM + tid * 4);
        a4[0] = fmaf(s, p.x, a4[0]);
        a4[1] = fmaf(s, p.y, a4[1]);
        a4[2] = fmaf(s, p.z, a4[2]);
        a4[3] = fmaf(s, p.w, a4[3]);
    }
    *(f32x4*)(ctx + (size_t)n * E_DIM + tid * 4) = a4;
    for (int t = tid; t < T_DIM; t += 256)
        alpha[t * N_DIM + n] = __expf(scores[t * N_DIM + n] - M) * invZ;
}

// ---------------- fallback path (small ws): softmax + fp32 ctx ------------
__global__ __launch_bounds__(256) void softmax_kernel(
    const float* __restrict__ scores, float* __restrict__ alpha) {
    __shared__ float red[256];
    const int n = blockIdx.x;
    const int tid = threadIdx.x;
    float m = -3.4e38f;
    for (int t = tid; t < T_DIM; t += 256)
        m = fmaxf(m, scores[t * N_DIM + n]);
    red[tid] = m;
    __syncthreads();
    for (int s = 128; s; s >>= 1) {
        if (tid < s) red[tid] = fmaxf(red[tid], red[tid + s]);
        __syncthreads();
    }
    m = red[0];
    __syncthreads();
    float sum = 0.f;
    for (int t = tid; t < T_DIM; t += 256)
        sum += expf(scores[t * N_DIM + n] - m);
    red[tid] = sum;
    __syncthreads();
    for (int s = 128; s; s >>= 1) {
        if (tid < s) red[tid] += red[tid + s];
        __syncthreads();
    }
    const float inv = 1.f / red[0];
    for (int t = tid; t < T_DIM; t += 256)
        alpha[t * N_DIM + n] = expf(scores[t * N_DIM + n] - m) * inv;
}

__global__ __launch_bounds__(256) void ctx_f32(const float* __restrict__ enc,
                                               const float* __restrict__ alpha,
                                               float* __restrict__ ctx) {
    const int n = blockIdx.x;
    const int tid = threadIdx.x;
    float4 acc = {0.f, 0.f, 0.f, 0.f};
    for (int t = 0; t < T_DIM; ++t) {
        const float al = alpha[t * N_DIM + n];
        float4 ev = *reinterpret_cast<const float4*>(
            enc + (size_t)(t * N_DIM + n) * E_DIM + tid * 4);
        acc.x = fmaf(al, ev.x, acc.x);
        acc.y = fmaf(al, ev.y, acc.y);
        acc.z = fmaf(al, ev.z, acc.z);
        acc.w = fmaf(al, ev.w, acc.w);
    }
    *reinterpret_cast<float4*>(ctx + (size_t)n * E_DIM + tid * 4) = acc;
}

extern "C" void kernel_launch(void* const* d_in, const int* in_sizes, int n_in,
                              void* d_out, int out_size, void* d_ws,
                              size_t ws_size, hipStream_t stream) {
    const float* enc = (const float*)d_in[0];    // [T,N,E]
    const float* dec_h = (const float*)d_in[1];  // [N,D]
    const float* W_e = (const float*)d_in[2];    // [A,E]
    const float* W_d = (const float*)d_in[3];    // [A,D]
    const float* v = (const float*)d_in[4];      // [1,A]

    float* out = (float*)d_out;
    float* ctx = out;            // 64*1024
    float* alpha = out + 65536;  // 2048*64

    float* ws = (float*)d_ws;
    float* d_proj = ws;                   // 16384 f
    float* scores = ws + 16384;           // 131072 f
    __bf16* Wp = (__bf16*)(ws + 147456);  // 131072 f worth
    float* ms = ws + 278528;              // 4096 f
    float* zs = ws + 282624;              // 4096 f
    float* partial = ws + 286720;         // 64*65536 = 4194304 f

    const size_t need =
        (size_t)(286720 + NCHUNK * N_DIM * E_DIM) * sizeof(float);
    const bool big = ws_size >= need;

    prep_kernel<<<192, 256, 0, stream>>>(W_e, dec_h, W_d, Wp, d_proj);
    flash_kernel<<<T_DIM / TCHUNK * N_DIM, 512, 0, stream>>>(
        enc, Wp, d_proj, v, scores, big ? partial : nullptr, ms, zs);
    if (big) {
        combine_kernel<<<N_DIM, 256, 0, stream>>>(partial, ms, zs, scores,
                                                  ctx, alpha);
    } else {
        softmax_kernel<<<N_DIM, 256, 0, stream>>>(scores, alpha);
        ctx_f32<<<N_DIM, 256, 0, stream>>>(enc, alpha, ctx);
    }
}